// Round 16
// baseline (76.604 us; speedup 1.0000x reference)
//
#include <hip/hip_runtime.h>

#define HH 128
#define NN 64
#define LL 256
#define WP 280   // u16 pitch: 140 dwords = 12 mod 32 -> near-conflict-free b128 rows

typedef __attribute__((ext_vector_type(8))) short bf8;
typedef __attribute__((ext_vector_type(4))) float f32x4;

__device__ inline ushort f2bf(float f) {
    uint x = __float_as_uint(f);
    return (ushort)((x + 0x7fffu + ((x >> 16) & 1u)) >> 16);
}
__device__ inline uint cvt_pk_bf16(float lo, float hi) {
    uint r;
    asm volatile("v_cvt_pk_bf16_f32 %0, %1, %2" : "=v"(r) : "v"(lo), "v"(hi));
    return r;
}
#define MFMA(a,b,c) __builtin_amdgcn_mfma_f32_16x16x32_bf16((a),(b),(c),0,0,0)

// Tap generation. Output parity-split pair tables per (s,h):
// arrg[(s*HH+h)*512 + j]       = rev[2j]   | rev[2j+1]<<16   (arrE)
// arrg[(s*HH+h)*512 + 256 + j] = rev[2j+1] | rev[2j+2]<<16   (arrO, rev[512]=0)
__global__ __launch_bounds__(512) void ssm_gen_fast(
    const float* __restrict__ A_re0, const float* __restrict__ A_im0,
    const float* __restrict__ C_re0, const float* __restrict__ C_im0,
    const float* __restrict__ log_dt0,
    const float* __restrict__ A_re1, const float* __restrict__ A_im1,
    const float* __restrict__ C_re1, const float* __restrict__ C_im1,
    const float* __restrict__ log_dt1,
    uint* __restrict__ arrg)
{
    __shared__ float4 par[128];
    __shared__ float  red[512];
    __shared__ ushort rev[512];

    int tid = threadIdx.x;
    int h   = blockIdx.x;
    int s   = blockIdx.y;

    if (tid < 128) {
        int n  = tid & 63;
        int ch = tid >> 6;
        const float* Ar = s ? A_re1 : A_re0;
        const float* Ai = s ? A_im1 : A_im0;
        const float* Cr = s ? C_re1 : C_re0;
        const float* Ci = s ? C_im1 : C_im0;
        const float* Ld = s ? log_dt1 : log_dt0;
        float dt = __expf(Ld[h]);
        float ar = Ar[h*NN + n], ai = Ai[h*NN + n];
        float cr = Cr[(ch*HH + h)*NN + n], ci = Ci[(ch*HH + h)*NN + n];
        float xr = dt * ar, xi = dt * ai;
        float phr = xi * 0.15915494f;
        float phf = phr - floorf(phr);
        float sn = __sinf(6.2831853f * phf);
        float cs = __cosf(6.2831853f * phf);
        float e  = __expf(xr);
        float er = e*cs - 1.f, ei = e*sn;
        float inv = 1.f / (ar*ar + ai*ai);
        float dr = (er*ar + ei*ai) * inv;
        float di = (ei*ar - er*ai) * inv;
        float Kr = 2.f*(cr*dr - ci*di);
        float Ki = 2.f*(cr*di + ci*dr);
        par[tid] = (float4){ xr, xi * 0.15915494f, Kr, Ki };
    }
    __syncthreads();

    {
        int l  = tid & 255;
        int ch = tid >> 8;
        float lf = (float)l;
#pragma unroll
        for (int nh = 0; nh < 2; ++nh) {
            const float4* pb = &par[ch*64 + nh*32];
            float acc = 0.f;
            for (int n = 0; n < 32; ++n) {
                float4 p = pb[n];
                float mag = __expf(p.x * lf);
                float ph  = p.y * lf;
                float phf = ph - floorf(ph);
                float ang = 6.2831853f * phf;
                acc += p.z * (mag * __cosf(ang)) - p.w * (mag * __sinf(ang));
            }
            if (nh == 0) red[tid] = acc;
            else {
                int ri = ch ? (256 + l) : (255 - l);
                rev[ri] = f2bf(red[tid] + acc);
            }
        }
    }
    __syncthreads();

    {
        int j  = tid & 255;
        uint lo, hi;
        if (tid < 256) { lo = rev[2*j];     hi = rev[2*j + 1]; }
        else           { lo = rev[2*j + 1]; hi = (j == 255) ? 0u : (uint)rev[2*j + 2]; }
        arrg[(s*HH + h)*512 + tid] = lo | (hi << 16);
    }
}

// Wave-specialized fused S4ND: one persistent block per bh (256 blocks, 1/CU).
// 8 waves = 2 groups of 4. Step s: group (s&1) produces quarter s (HBM->MFMA->WT),
// other group consumes quarter s-1 (WT->MFMA->store). HBM read+write continuous.
__global__ __launch_bounds__(512, 2) void s4nd_ws(
    const float* __restrict__ u, const float* __restrict__ Dv,
    const uint* __restrict__ arrg, float* __restrict__ out)
{
    __shared__ ushort WT0[64 * WP];       // 35840 B
    __shared__ ushort WT1[64 * WP];       // 35840 B
    __shared__ uint   arr[2][512];        // 4096 B

    int tid = threadIdx.x;
    int j   = blockIdx.x;
    int bh  = (j & 7) * 32 + (j >> 3);    // XCD-major spread
    int h   = bh & (HH - 1);

    arr[0][tid] = arrg[h*512 + tid];
    arr[1][tid] = arrg[(HH + h)*512 + tid];
    __syncthreads();

    int lane = tid & 63;
    int w    = tid >> 6;                  // 0..7
    int c    = lane & 15, q = lane >> 4;
    int grp  = w >> 2;                    // 0/1
    int sub  = w & 3;                     // role-local index

    const uint* T1 = &arr[0][(c & 1) ? 0 : 256];
    const uint* T2 = &arr[1][(c & 1) ? 0 : 256];

    const float* ub = u + (size_t)bh * LL * LL;
    float* yb_ = out + (size_t)bh * LL * LL;
    float dh = Dv[h];

    // producer row pointers: x rows sub*64 + 16ni + c
    const float* rp[4];
#pragma unroll
    for (int ni = 0; ni < 4; ++ni)
        rp[ni] = ub + (size_t)(sub*64 + 16*ni + c) * LL;

    int jbC = (255 - 64*sub - c + 8*q) >> 1;   // consumer window base

    f32x4 acc[16];
#pragma unroll
    for (int i = 0; i < 16; ++i) acc[i] = (f32x4){0.f,0.f,0.f,0.f};

    for (int s = 0; s < 5; ++s) {
        bool isProd = (s < 4) && ((s & 1) == grp);
        bool isCons = (s >= 1) && (((s - 1) & 1) == grp);

        if (isProd) {
            int qt = s;
            int yq = qt * 64;
            ushort* wtb = (qt & 1) ? WT1 : WT0;
            int jb = (255 - yq - c + 8*q) >> 1;
            bf8 win[4];
#pragma unroll
            for (int t = -3; t <= 0; ++t) {
                int jj = jb + 8*t;
                uint* pw = (uint*)&win[t & 3];
                pw[0] = T2[jj]; pw[1] = T2[jj+1]; pw[2] = T2[jj+2]; pw[3] = T2[jj+3];
            }
#pragma unroll
            for (int kk = 0; kk < 8; ++kk) {
                if (kk) {
#pragma unroll
                    for (int t = 2*kk - 1; t <= 2*kk; ++t) {
                        int jj = jb + 8*t;
                        uint* pw = (uint*)&win[t & 3];
                        pw[0] = T2[jj]; pw[1] = T2[jj+1]; pw[2] = T2[jj+2]; pw[3] = T2[jj+3];
                    }
                }
                int yb = kk*32 + 8*q;
                bf8 b[4];
#pragma unroll
                for (int ni = 0; ni < 4; ++ni) {
                    float4 fa = *(const float4*)(rp[ni] + yb);
                    float4 fb = *(const float4*)(rp[ni] + yb + 4);
                    uint* pb = (uint*)&b[ni];
                    pb[0] = cvt_pk_bf16(fa.x, fa.y); pb[1] = cvt_pk_bf16(fa.z, fa.w);
                    pb[2] = cvt_pk_bf16(fb.x, fb.y); pb[3] = cvt_pk_bf16(fb.z, fb.w);
                }
                __builtin_amdgcn_s_setprio(1);
#pragma unroll
                for (int mi = 0; mi < 4; ++mi) {
                    bf8 a = win[(2*kk - mi) & 3];
#pragma unroll
                    for (int ni = 0; ni < 4; ++ni)
                        acc[mi*4 + ni] = MFMA(a, b[ni], acc[mi*4 + ni]);
                }
                __builtin_amdgcn_s_setprio(0);
            }
            // acc -> WT (quarter-local rows), zero acc
#pragma unroll
            for (int mi = 0; mi < 4; ++mi)
#pragma unroll
                for (int ni = 0; ni < 4; ++ni)
#pragma unroll
                    for (int r = 0; r < 4; ++r) {
                        int row = 16*mi + 4*q + r;
                        int col = sub*64 + 16*ni + c;
                        wtb[row*WP + col] = f2bf(acc[mi*4 + ni][r]);
                        acc[mi*4 + ni][r] = 0.f;
                    }
        } else if (isCons) {
            int qt = s - 1;
            int yq = qt * 64;
            const ushort* wtb = (qt & 1) ? WT1 : WT0;
            bf8 win2[4];
#pragma unroll
            for (int t = -3; t <= 0; ++t) {
                int jj = jbC + 8*t;
                uint* pw = (uint*)&win2[t & 3];
                pw[0] = T1[jj]; pw[1] = T1[jj+1]; pw[2] = T1[jj+2]; pw[3] = T1[jj+3];
            }
#pragma unroll
            for (int kk = 0; kk < 8; ++kk) {
                if (kk) {
#pragma unroll
                    for (int t = 2*kk - 1; t <= 2*kk; ++t) {
                        int jj = jbC + 8*t;
                        uint* pw = (uint*)&win2[t & 3];
                        pw[0] = T1[jj]; pw[1] = T1[jj+1]; pw[2] = T1[jj+2]; pw[3] = T1[jj+3];
                    }
                }
                int xb = kk*32 + 8*q;
                bf8 b[4];
#pragma unroll
                for (int ni = 0; ni < 4; ++ni)
                    b[ni] = *(const bf8*)&wtb[(16*ni + c)*WP + xb];
                __builtin_amdgcn_s_setprio(1);
#pragma unroll
                for (int mi = 0; mi < 4; ++mi) {
                    bf8 a = win2[(2*kk - mi) & 3];
#pragma unroll
                    for (int ni = 0; ni < 4; ++ni)
                        acc[mi*4 + ni] = MFMA(a, b[ni], acc[mi*4 + ni]);
                }
                __builtin_amdgcn_s_setprio(0);
            }
            // epilogue: Y + D*u -> global, zero acc
#pragma unroll
            for (int mi = 0; mi < 4; ++mi) {
                float uh[16];
#pragma unroll
                for (int ni = 0; ni < 4; ++ni)
#pragma unroll
                    for (int r = 0; r < 4; ++r) {
                        int row = 64*sub + 16*mi + 4*q + r;
                        int col = yq + 16*ni + c;
                        uh[ni*4 + r] = ub[(size_t)row*LL + col];
                    }
#pragma unroll
                for (int ni = 0; ni < 4; ++ni)
#pragma unroll
                    for (int r = 0; r < 4; ++r) {
                        int row = 64*sub + 16*mi + 4*q + r;
                        int col = yq + 16*ni + c;
                        yb_[(size_t)row*LL + col] =
                            acc[mi*4 + ni][r] + dh * uh[ni*4 + r];
                        acc[mi*4 + ni][r] = 0.f;
                    }
            }
        }
        __syncthreads();
    }
}

extern "C" void kernel_launch(void* const* d_in, const int* in_sizes, int n_in,
                              void* d_out, int out_size, void* d_ws, size_t ws_size,
                              hipStream_t stream)
{
    const float* u       = (const float*)d_in[0];
    const float* D       = (const float*)d_in[1];
    const float* A_re0   = (const float*)d_in[2];
    const float* A_im0   = (const float*)d_in[3];
    const float* C_re0   = (const float*)d_in[4];
    const float* C_im0   = (const float*)d_in[5];
    const float* log_dt0 = (const float*)d_in[6];
    const float* A_re1   = (const float*)d_in[7];
    const float* A_im1   = (const float*)d_in[8];
    const float* C_re1   = (const float*)d_in[9];
    const float* C_im1   = (const float*)d_in[10];
    const float* log_dt1 = (const float*)d_in[11];
    float* out = (float*)d_out;

    uint* arrg = (uint*)d_ws;   // 2*128*512 u32 = 512 KB

    ssm_gen_fast<<<dim3(HH, 2), 512, 0, stream>>>(
        A_re0, A_im0, C_re0, C_im0, log_dt0,
        A_re1, A_im1, C_re1, C_im1, log_dt1, arrg);
    s4nd_ws<<<256, 512, 0, stream>>>(u, D, arrg, out);
}

// Round 18
// 53.285 us; speedup vs baseline: 1.4376x; 1.4376x over previous
//
#include <hip/hip_runtime.h>

#define HH 128
#define NN 64
#define LL 256
#define WP 280   // u16 pitch: 140 dwords = 12 mod 32 -> near-conflict-free b128 rows

typedef __attribute__((ext_vector_type(8))) short bf8;
typedef __attribute__((ext_vector_type(4))) float f32x4;

__device__ inline ushort f2bf(float f) {
    uint x = __float_as_uint(f);
    return (ushort)((x + 0x7fffu + ((x >> 16) & 1u)) >> 16);
}
__device__ inline uint cvt_pk_bf16(float lo, float hi) {
    uint r;
    asm volatile("v_cvt_pk_bf16_f32 %0, %1, %2" : "=v"(r) : "v"(lo), "v"(hi));
    return r;
}
#define MFMA(a,b,c) __builtin_amdgcn_mfma_f32_16x16x32_bf16((a),(b),(c),0,0,0)

// Tap generation. Output parity-split pair tables per (s,h):
// arrg[(s*HH+h)*512 + j]       = rev[2j]   | rev[2j+1]<<16   (arrE)
// arrg[(s*HH+h)*512 + 256 + j] = rev[2j+1] | rev[2j+2]<<16   (arrO, rev[512]=0)
__global__ __launch_bounds__(512) void ssm_gen_fast(
    const float* __restrict__ A_re0, const float* __restrict__ A_im0,
    const float* __restrict__ C_re0, const float* __restrict__ C_im0,
    const float* __restrict__ log_dt0,
    const float* __restrict__ A_re1, const float* __restrict__ A_im1,
    const float* __restrict__ C_re1, const float* __restrict__ C_im1,
    const float* __restrict__ log_dt1,
    uint* __restrict__ arrg)
{
    __shared__ float4 par[128];
    __shared__ float  red[512];
    __shared__ ushort rev[512];

    int tid = threadIdx.x;
    int h   = blockIdx.x;
    int s   = blockIdx.y;

    if (tid < 128) {
        int n  = tid & 63;
        int ch = tid >> 6;
        const float* Ar = s ? A_re1 : A_re0;
        const float* Ai = s ? A_im1 : A_im0;
        const float* Cr = s ? C_re1 : C_re0;
        const float* Ci = s ? C_im1 : C_im0;
        const float* Ld = s ? log_dt1 : log_dt0;
        float dt = __expf(Ld[h]);
        float ar = Ar[h*NN + n], ai = Ai[h*NN + n];
        float cr = Cr[(ch*HH + h)*NN + n], ci = Ci[(ch*HH + h)*NN + n];
        float xr = dt * ar, xi = dt * ai;
        float phr = xi * 0.15915494f;
        float phf = phr - floorf(phr);
        float sn = __sinf(6.2831853f * phf);
        float cs = __cosf(6.2831853f * phf);
        float e  = __expf(xr);
        float er = e*cs - 1.f, ei = e*sn;
        float inv = 1.f / (ar*ar + ai*ai);
        float dr = (er*ar + ei*ai) * inv;
        float di = (ei*ar - er*ai) * inv;
        float Kr = 2.f*(cr*dr - ci*di);
        float Ki = 2.f*(cr*di + ci*dr);
        par[tid] = (float4){ xr, xi * 0.15915494f, Kr, Ki };
    }
    __syncthreads();

    {
        int l  = tid & 255;
        int ch = tid >> 8;
        float lf = (float)l;
#pragma unroll
        for (int nh = 0; nh < 2; ++nh) {
            const float4* pb = &par[ch*64 + nh*32];
            float acc = 0.f;
            for (int n = 0; n < 32; ++n) {
                float4 p = pb[n];
                float mag = __expf(p.x * lf);
                float ph  = p.y * lf;
                float phf = ph - floorf(ph);
                float ang = 6.2831853f * phf;
                acc += p.z * (mag * __cosf(ang)) - p.w * (mag * __sinf(ang));
            }
            if (nh == 0) red[tid] = acc;
            else {
                int ri = ch ? (256 + l) : (255 - l);
                rev[ri] = f2bf(red[tid] + acc);
            }
        }
    }
    __syncthreads();

    {
        int j  = tid & 255;
        uint lo, hi;
        if (tid < 256) { lo = rev[2*j];     hi = rev[2*j + 1]; }
        else           { lo = rev[2*j + 1]; hi = (j == 255) ? 0u : (uint)rev[2*j + 2]; }
        arrg[(s*HH + h)*512 + tid] = lo | (hi << 16);
    }
}

// asm depth-2 staging primitives
#define GL0(dst, addr)  asm volatile("global_load_dwordx4 %0, %1, off"           : "=v"(dst) : "v"(addr))
#define GL16(dst, addr) asm volatile("global_load_dwordx4 %0, %1, off offset:16" : "=v"(dst) : "v"(addr))
#define VMW(n) do { asm volatile("s_waitcnt vmcnt(" #n ")" ::: "memory"); \
                    __builtin_amdgcn_sched_barrier(0); } while (0)

#define WINROLL8(T, JB, t_)                                                   \
    { int jj = (JB) + 8*(t_); uint* pw = (uint*)&win[(t_) & 7];               \
      pw[0]=T[jj]; pw[1]=T[jj+1]; pw[2]=T[jj+2]; pw[3]=T[jj+3]; }

// one ph1 kk-step: issue next loads, roll window, wait current, cvt, MFMA
#define PH1_KK(kk, C0, C1, N0, N1)                                            \
    {                                                                         \
        { const float* a_ = rp + ((kk)+1)*32 + 8*q;                           \
          GL0(N0, a_); GL16(N1, a_); }                                        \
        if ((kk) > 0) { WINROLL8(T2, jb2, 2*(kk)-1); WINROLL8(T2, jb2, 2*(kk)); } \
        VMW(2);                                                               \
        bf8 b0_; uint* pb_ = (uint*)&b0_;                                     \
        pb_[0]=cvt_pk_bf16(C0.x,C0.y); pb_[1]=cvt_pk_bf16(C0.z,C0.w);         \
        pb_[2]=cvt_pk_bf16(C1.x,C1.y); pb_[3]=cvt_pk_bf16(C1.z,C1.w);         \
        __builtin_amdgcn_s_setprio(1);                                        \
        _Pragma("unroll")                                                     \
        for (int mi = 0; mi < 8; ++mi)                                        \
            acc[mi] = MFMA(win[(2*(kk)-mi) & 7], b0_, acc[mi]);               \
        __builtin_amdgcn_s_setprio(0);                                        \
    }

#define PH1_KK7(C0, C1)                                                       \
    {                                                                         \
        WINROLL8(T2, jb2, 13); WINROLL8(T2, jb2, 14);                         \
        VMW(0);                                                               \
        bf8 b0_; uint* pb_ = (uint*)&b0_;                                     \
        pb_[0]=cvt_pk_bf16(C0.x,C0.y); pb_[1]=cvt_pk_bf16(C0.z,C0.w);         \
        pb_[2]=cvt_pk_bf16(C1.x,C1.y); pb_[3]=cvt_pk_bf16(C1.z,C1.w);         \
        __builtin_amdgcn_s_setprio(1);                                        \
        _Pragma("unroll")                                                     \
        for (int mi = 0; mi < 8; ++mi)                                        \
            acc[mi] = MFMA(win[(14-mi) & 7], b0_, acc[mi]);                   \
        __builtin_amdgcn_s_setprio(0);                                        \
    }

// Fused S4ND per (b, h, y-half), 512 threads / 8 waves, 2 blocks/CU.
// ph1: two x-substrip passes (acc[8], true asm depth-2 u pipeline).
// ph2: two y'-strip passes (acc[8]), nt stores.
__global__ __launch_bounds__(512, 4) void s4nd_v5(
    const float* __restrict__ u, const float* __restrict__ Dv,
    const uint* __restrict__ arrg, float* __restrict__ out)
{
    __shared__ ushort WT[128 * WP];       // 71680 B
    __shared__ uint   arr[2][512];        // 4096 B

    int tid = threadIdx.x;
    int j    = blockIdx.x;
    int xcd  = j & 7;
    int k    = j >> 3;
    int bh   = xcd * 32 + (k >> 1);
    int y0   = (k & 1) * 128;
    int h    = bh & (HH - 1);

    arr[0][tid] = arrg[h*512 + tid];
    arr[1][tid] = arrg[(HH + h)*512 + tid];
    __syncthreads();

    int lane = tid & 63;
    int w = tid >> 6;
    int c = lane & 15, q = lane >> 4;
    int wm2 = (w >> 1) * 64, wn2 = (w & 1) * 64;

    const uint* T1 = &arr[0][(c & 1) ? 0 : 256];
    const uint* T2 = &arr[1][(c & 1) ? 0 : 256];
    int jb2 = (255 - y0  - c + 8*q) >> 1;
    int jb1 = (255 - wm2 - c + 8*q) >> 1;

    f32x4 acc[8];
#pragma unroll
    for (int i = 0; i < 8; ++i) acc[i] = (f32x4){0.f,0.f,0.f,0.f};

    const float* ub = u + (size_t)bh * LL * LL;
    float* yb_ = out + (size_t)bh * LL * LL;

    // ---- phase 1: x-substrips ns=0,1 (disjoint rows -> u read once) ----
#pragma unroll
    for (int ns = 0; ns < 2; ++ns) {
        const float* rp = ub + (size_t)(w*32 + 16*ns + c) * LL;
        bf8 win[8];
#pragma unroll
        for (int t = -7; t <= 0; ++t) WINROLL8(T2, jb2, t);
        float4 SA0, SA1, SB0, SB1;
        { const float* a_ = rp + 8*q; GL0(SA0, a_); GL16(SA1, a_); }
        PH1_KK(0, SA0, SA1, SB0, SB1)
        PH1_KK(1, SB0, SB1, SA0, SA1)
        PH1_KK(2, SA0, SA1, SB0, SB1)
        PH1_KK(3, SB0, SB1, SA0, SA1)
        PH1_KK(4, SA0, SA1, SB0, SB1)
        PH1_KK(5, SB0, SB1, SA0, SA1)
        PH1_KK(6, SA0, SA1, SB0, SB1)
        PH1_KK7(SB0, SB1)
        // acc -> WT, zero acc
#pragma unroll
        for (int mi = 0; mi < 8; ++mi)
#pragma unroll
            for (int r = 0; r < 4; ++r) {
                int row = 16*mi + 4*q + r;
                WT[row*WP + w*32 + 16*ns + c] = f2bf(acc[mi][r]);
                acc[mi][r] = 0.f;
            }
    }
    __syncthreads();

    // ---- phase 2: two y'-strip passes, nt stores ----
    float dh = Dv[h];
#pragma unroll
    for (int p = 0; p < 2; ++p) {
        int nb = wn2 + p*32;

        float uh[32];
#pragma unroll
        for (int mi = 0; mi < 4; ++mi)
#pragma unroll
            for (int r = 0; r < 4; ++r) {
                int row = wm2 + 16*mi + 4*q + r;
#pragma unroll
                for (int ni = 0; ni < 2; ++ni)
                    uh[(mi*4 + r)*2 + ni] = ub[(size_t)row*LL + y0 + nb + 16*ni + c];
            }

        bf8 win2[4];
#pragma unroll
        for (int t = -3; t <= 0; ++t) {
            int jj = jb1 + 8*t;
            uint* pw = (uint*)&win2[t & 3];
            pw[0]=T1[jj]; pw[1]=T1[jj+1]; pw[2]=T1[jj+2]; pw[3]=T1[jj+3];
        }
#pragma unroll
        for (int kk = 0; kk < 8; ++kk) {
            if (kk) {
#pragma unroll
                for (int t = 2*kk - 1; t <= 2*kk; ++t) {
                    int jj = jb1 + 8*t;
                    uint* pw = (uint*)&win2[t & 3];
                    pw[0]=T1[jj]; pw[1]=T1[jj+1]; pw[2]=T1[jj+2]; pw[3]=T1[jj+3];
                }
            }
            int xb = kk*32 + 8*q;
            bf8 b0 = *(const bf8*)&WT[(nb + c)*WP + xb];
            bf8 b1 = *(const bf8*)&WT[(nb + 16 + c)*WP + xb];
            __builtin_amdgcn_s_setprio(1);
#pragma unroll
            for (int mi = 0; mi < 4; ++mi) {
                bf8 a = win2[(2*kk - mi) & 3];
                acc[mi*2 + 0] = MFMA(a, b0, acc[mi*2 + 0]);
                acc[mi*2 + 1] = MFMA(a, b1, acc[mi*2 + 1]);
            }
            __builtin_amdgcn_s_setprio(0);
        }

        // stores (+D*u), non-temporal, zero acc
#pragma unroll
        for (int mi = 0; mi < 4; ++mi)
#pragma unroll
            for (int ni = 0; ni < 2; ++ni)
#pragma unroll
                for (int r = 0; r < 4; ++r) {
                    int row = wm2 + 16*mi + 4*q + r;
                    int col = y0 + nb + 16*ni + c;
                    float v = acc[mi*2 + ni][r] + dh * uh[(mi*4 + r)*2 + ni];
                    __builtin_nontemporal_store(v, &yb_[(size_t)row*LL + col]);
                    acc[mi*2 + ni][r] = 0.f;
                }
    }
}

extern "C" void kernel_launch(void* const* d_in, const int* in_sizes, int n_in,
                              void* d_out, int out_size, void* d_ws, size_t ws_size,
                              hipStream_t stream)
{
    const float* u       = (const float*)d_in[0];
    const float* D       = (const float*)d_in[1];
    const float* A_re0   = (const float*)d_in[2];
    const float* A_im0   = (const float*)d_in[3];
    const float* C_re0   = (const float*)d_in[4];
    const float* C_im0   = (const float*)d_in[5];
    const float* log_dt0 = (const float*)d_in[6];
    const float* A_re1   = (const float*)d_in[7];
    const float* A_im1   = (const float*)d_in[8];
    const float* C_re1   = (const float*)d_in[9];
    const float* C_im1   = (const float*)d_in[10];
    const float* log_dt1 = (const float*)d_in[11];
    float* out = (float*)d_out;

    uint* arrg = (uint*)d_ws;   // 2*128*512 u32 = 512 KB

    ssm_gen_fast<<<dim3(HH, 2), 512, 0, stream>>>(
        A_re0, A_im0, C_re0, C_im0, log_dt0,
        A_re1, A_im1, C_re1, C_im1, log_dt1, arrg);
    s4nd_v5<<<512, 512, 0, stream>>>(u, D, arrg, out);
}

// Round 19
// 49.562 us; speedup vs baseline: 1.5456x; 1.0751x over previous
//
#include <hip/hip_runtime.h>

#define HH 128
#define NN 64
#define LL 256
#define WP 280   // u16 pitch: 140 dwords = 12 mod 32 -> near-conflict-free b128 rows

typedef __attribute__((ext_vector_type(8))) short bf8;
typedef __attribute__((ext_vector_type(4))) float f32x4;

__device__ inline ushort f2bf(float f) {
    uint x = __float_as_uint(f);
    return (ushort)((x + 0x7fffu + ((x >> 16) & 1u)) >> 16);
}
__device__ inline uint cvt_pk_bf16(float lo, float hi) {
    uint r;
    asm volatile("v_cvt_pk_bf16_f32 %0, %1, %2" : "=v"(r) : "v"(lo), "v"(hi));
    return r;
}
#define MFMA(a,b,c) __builtin_amdgcn_mfma_f32_16x16x32_bf16((a),(b),(c),0,0,0)

// Tap generation. Output parity-split pair tables per (s,h):
// arrg[(s*HH+h)*512 + j]       = rev[2j]   | rev[2j+1]<<16   (arrE)
// arrg[(s*HH+h)*512 + 256 + j] = rev[2j+1] | rev[2j+2]<<16   (arrO, rev[512]=0)
__global__ __launch_bounds__(512) void ssm_gen_fast(
    const float* __restrict__ A_re0, const float* __restrict__ A_im0,
    const float* __restrict__ C_re0, const float* __restrict__ C_im0,
    const float* __restrict__ log_dt0,
    const float* __restrict__ A_re1, const float* __restrict__ A_im1,
    const float* __restrict__ C_re1, const float* __restrict__ C_im1,
    const float* __restrict__ log_dt1,
    uint* __restrict__ arrg)
{
    __shared__ float4 par[128];
    __shared__ float  red[512];
    __shared__ ushort rev[512];

    int tid = threadIdx.x;
    int h   = blockIdx.x;
    int s   = blockIdx.y;

    if (tid < 128) {
        int n  = tid & 63;
        int ch = tid >> 6;
        const float* Ar = s ? A_re1 : A_re0;
        const float* Ai = s ? A_im1 : A_im0;
        const float* Cr = s ? C_re1 : C_re0;
        const float* Ci = s ? C_im1 : C_im0;
        const float* Ld = s ? log_dt1 : log_dt0;
        float dt = __expf(Ld[h]);
        float ar = Ar[h*NN + n], ai = Ai[h*NN + n];
        float cr = Cr[(ch*HH + h)*NN + n], ci = Ci[(ch*HH + h)*NN + n];
        float xr = dt * ar, xi = dt * ai;
        float phr = xi * 0.15915494f;
        float phf = phr - floorf(phr);
        float sn = __sinf(6.2831853f * phf);
        float cs = __cosf(6.2831853f * phf);
        float e  = __expf(xr);
        float er = e*cs - 1.f, ei = e*sn;
        float inv = 1.f / (ar*ar + ai*ai);
        float dr = (er*ar + ei*ai) * inv;
        float di = (ei*ar - er*ai) * inv;
        float Kr = 2.f*(cr*dr - ci*di);
        float Ki = 2.f*(cr*di + ci*dr);
        par[tid] = (float4){ xr, xi * 0.15915494f, Kr, Ki };
    }
    __syncthreads();

    {
        int l  = tid & 255;
        int ch = tid >> 8;
        float lf = (float)l;
#pragma unroll
        for (int nh = 0; nh < 2; ++nh) {
            const float4* pb = &par[ch*64 + nh*32];
            float acc = 0.f;
            for (int n = 0; n < 32; ++n) {
                float4 p = pb[n];
                float mag = __expf(p.x * lf);
                float ph  = p.y * lf;
                float phf = ph - floorf(ph);
                float ang = 6.2831853f * phf;
                acc += p.z * (mag * __cosf(ang)) - p.w * (mag * __sinf(ang));
            }
            if (nh == 0) red[tid] = acc;
            else {
                int ri = ch ? (256 + l) : (255 - l);
                rev[ri] = f2bf(red[tid] + acc);
            }
        }
    }
    __syncthreads();

    {
        int j  = tid & 255;
        uint lo, hi;
        if (tid < 256) { lo = rev[2*j];     hi = rev[2*j + 1]; }
        else           { lo = rev[2*j + 1]; hi = (j == 255) ? 0u : (uint)rev[2*j + 2]; }
        arrg[(s*HH + h)*512 + tid] = lo | (hi << 16);
    }
}

// asm pipeline primitives
#define GL0(dst, addr)  asm volatile("global_load_dwordx4 %0, %1, off"           : "=v"(dst) : "v"(addr))
#define GL16(dst, addr) asm volatile("global_load_dwordx4 %0, %1, off offset:16" : "=v"(dst) : "v"(addr))
#define VMW(n) do { asm volatile("s_waitcnt vmcnt(" #n ")" ::: "memory"); \
                    __builtin_amdgcn_sched_barrier(0); } while (0)

#define WINROLL8(T, JB, t_)                                                   \
    { int jj = (JB) + 8*(t_); uint* pw = (uint*)&win[(t_) & 7];               \
      pw[0]=T[jj]; pw[1]=T[jj+1]; pw[2]=T[jj+2]; pw[3]=T[jj+3]; }

// issue loads for k-step kk into bank (N0,N1)
#define PH1_ISS(kk, N0, N1)                                                   \
    { const float* a_ = rp + (kk)*32 + 8*q; GL0(N0, a_); GL16(N1, a_); }

// consume k-step kk from bank (C0,C1) after waiting to CNT outstanding
#define PH1_CON(kk, C0, C1, CNT)                                              \
    {                                                                         \
        if ((kk) > 0) { WINROLL8(T2, jb2, 2*(kk)-1); WINROLL8(T2, jb2, 2*(kk)); } \
        VMW(CNT);                                                             \
        bf8 b0_; uint* pb_ = (uint*)&b0_;                                     \
        pb_[0]=cvt_pk_bf16(C0.x,C0.y); pb_[1]=cvt_pk_bf16(C0.z,C0.w);         \
        pb_[2]=cvt_pk_bf16(C1.x,C1.y); pb_[3]=cvt_pk_bf16(C1.z,C1.w);         \
        __builtin_amdgcn_s_setprio(1);                                        \
        _Pragma("unroll")                                                     \
        for (int mi = 0; mi < 8; ++mi)                                        \
            acc[mi] = MFMA(win[(2*(kk)-mi) & 7], b0_, acc[mi]);               \
        __builtin_amdgcn_s_setprio(0);                                        \
    }

// Fused S4ND per (b, h, y-half), 512 threads / 8 waves, 2 blocks/CU.
// ph1: two x-substrip passes, depth-3 asm pipeline (vmcnt(4) steady).
// ph2: two y'-strip passes, normal stores.
__global__ __launch_bounds__(512, 4) void s4nd_v6(
    const float* __restrict__ u, const float* __restrict__ Dv,
    const uint* __restrict__ arrg, float* __restrict__ out)
{
    __shared__ ushort WT[128 * WP];       // 71680 B
    __shared__ uint   arr[2][512];        // 4096 B

    int tid = threadIdx.x;
    int j    = blockIdx.x;
    int xcd  = j & 7;
    int k    = j >> 3;
    int bh   = xcd * 32 + (k >> 1);
    int y0   = (k & 1) * 128;
    int h    = bh & (HH - 1);

    arr[0][tid] = arrg[h*512 + tid];
    arr[1][tid] = arrg[(HH + h)*512 + tid];
    __syncthreads();

    int lane = tid & 63;
    int w = tid >> 6;
    int c = lane & 15, q = lane >> 4;
    int wm2 = (w >> 1) * 64, wn2 = (w & 1) * 64;

    const uint* T1 = &arr[0][(c & 1) ? 0 : 256];
    const uint* T2 = &arr[1][(c & 1) ? 0 : 256];
    int jb2 = (255 - y0  - c + 8*q) >> 1;
    int jb1 = (255 - wm2 - c + 8*q) >> 1;

    f32x4 acc[8];
#pragma unroll
    for (int i = 0; i < 8; ++i) acc[i] = (f32x4){0.f,0.f,0.f,0.f};

    const float* ub = u + (size_t)bh * LL * LL;
    float* yb_ = out + (size_t)bh * LL * LL;

    // ---- phase 1: x-substrips ns=0,1; depth-3 rotating banks S0/S1/S2 ----
#pragma unroll
    for (int ns = 0; ns < 2; ++ns) {
        const float* rp = ub + (size_t)(w*32 + 16*ns + c) * LL;
        bf8 win[8];
#pragma unroll
        for (int t = -7; t <= 0; ++t) WINROLL8(T2, jb2, t);
        float4 S00, S01, S10, S11, S20, S21;
        PH1_ISS(0, S00, S01)
        PH1_ISS(1, S10, S11)
        PH1_ISS(2, S20, S21)  PH1_CON(0, S00, S01, 4)
        PH1_ISS(3, S00, S01)  PH1_CON(1, S10, S11, 4)
        PH1_ISS(4, S10, S11)  PH1_CON(2, S20, S21, 4)
        PH1_ISS(5, S20, S21)  PH1_CON(3, S00, S01, 4)
        PH1_ISS(6, S00, S01)  PH1_CON(4, S10, S11, 4)
        PH1_ISS(7, S10, S11)  PH1_CON(5, S20, S21, 4)
                              PH1_CON(6, S00, S01, 2)
                              PH1_CON(7, S10, S11, 0)
        // acc -> WT, zero acc
#pragma unroll
        for (int mi = 0; mi < 8; ++mi)
#pragma unroll
            for (int r = 0; r < 4; ++r) {
                int row = 16*mi + 4*q + r;
                WT[row*WP + w*32 + 16*ns + c] = f2bf(acc[mi][r]);
                acc[mi][r] = 0.f;
            }
    }
    __syncthreads();

    // ---- phase 2: two y'-strip passes ----
    float dh = Dv[h];
#pragma unroll
    for (int p = 0; p < 2; ++p) {
        int nb = wn2 + p*32;

        float uh[32];
#pragma unroll
        for (int mi = 0; mi < 4; ++mi)
#pragma unroll
            for (int r = 0; r < 4; ++r) {
                int row = wm2 + 16*mi + 4*q + r;
#pragma unroll
                for (int ni = 0; ni < 2; ++ni)
                    uh[(mi*4 + r)*2 + ni] = ub[(size_t)row*LL + y0 + nb + 16*ni + c];
            }

        bf8 win2[4];
#pragma unroll
        for (int t = -3; t <= 0; ++t) {
            int jj = jb1 + 8*t;
            uint* pw = (uint*)&win2[t & 3];
            pw[0]=T1[jj]; pw[1]=T1[jj+1]; pw[2]=T1[jj+2]; pw[3]=T1[jj+3];
        }
#pragma unroll
        for (int kk = 0; kk < 8; ++kk) {
            if (kk) {
#pragma unroll
                for (int t = 2*kk - 1; t <= 2*kk; ++t) {
                    int jj = jb1 + 8*t;
                    uint* pw = (uint*)&win2[t & 3];
                    pw[0]=T1[jj]; pw[1]=T1[jj+1]; pw[2]=T1[jj+2]; pw[3]=T1[jj+3];
                }
            }
            int xb = kk*32 + 8*q;
            bf8 b0 = *(const bf8*)&WT[(nb + c)*WP + xb];
            bf8 b1 = *(const bf8*)&WT[(nb + 16 + c)*WP + xb];
            __builtin_amdgcn_s_setprio(1);
#pragma unroll
            for (int mi = 0; mi < 4; ++mi) {
                bf8 a = win2[(2*kk - mi) & 3];
                acc[mi*2 + 0] = MFMA(a, b0, acc[mi*2 + 0]);
                acc[mi*2 + 1] = MFMA(a, b1, acc[mi*2 + 1]);
            }
            __builtin_amdgcn_s_setprio(0);
        }

        // stores (+D*u), zero acc
#pragma unroll
        for (int mi = 0; mi < 4; ++mi)
#pragma unroll
            for (int ni = 0; ni < 2; ++ni)
#pragma unroll
                for (int r = 0; r < 4; ++r) {
                    int row = wm2 + 16*mi + 4*q + r;
                    int col = y0 + nb + 16*ni + c;
                    yb_[(size_t)row*LL + col] =
                        acc[mi*2 + ni][r] + dh * uh[(mi*4 + r)*2 + ni];
                    acc[mi*2 + ni][r] = 0.f;
                }
    }
}

extern "C" void kernel_launch(void* const* d_in, const int* in_sizes, int n_in,
                              void* d_out, int out_size, void* d_ws, size_t ws_size,
                              hipStream_t stream)
{
    const float* u       = (const float*)d_in[0];
    const float* D       = (const float*)d_in[1];
    const float* A_re0   = (const float*)d_in[2];
    const float* A_im0   = (const float*)d_in[3];
    const float* C_re0   = (const float*)d_in[4];
    const float* C_im0   = (const float*)d_in[5];
    const float* log_dt0 = (const float*)d_in[6];
    const float* A_re1   = (const float*)d_in[7];
    const float* A_im1   = (const float*)d_in[8];
    const float* C_re1   = (const float*)d_in[9];
    const float* C_im1   = (const float*)d_in[10];
    const float* log_dt1 = (const float*)d_in[11];
    float* out = (float*)d_out;

    uint* arrg = (uint*)d_ws;   // 2*128*512 u32 = 512 KB

    ssm_gen_fast<<<dim3(HH, 2), 512, 0, stream>>>(
        A_re0, A_im0, C_re0, C_im0, log_dt0,
        A_re1, A_im1, C_re1, C_im1, log_dt1, arrg);
    s4nd_v6<<<512, 512, 0, stream>>>(u, D, arrg, out);
}